// Round 10
// baseline (811.440 us; speedup 1.0000x reference)
//
#include <hip/hip_runtime.h>
#include <math.h>

#define N     257    // state dim
#define AP    258    // doubles per A row (cols 0..256 = S, col 257 = rhs)
#define MM    128    // rotation pairs
#define LL    512    // seq length
#define BB    4      // batch
#define NBK   64     // panel width
#define USTR  196    // U12w row stride (doubles)
#define SPSTR 260    // padded S row stride (floats, 16B-aligned rows)

// ws byte layout:
#define A_BYTE    0         // double[257*258] = 530448
#define W0_BYTE   530448    // float[257]
#define CXY_BYTE  531488    // float[4096]
#define U12_BYTE  547904    // double[64*196] = 100352 -> ends 648256
#define SP_BYTE   648256    // float[257*260] = 267280 -> ends 915536

// ---------------------------------------------------------------------------
// prep: block 0 = prefix sums of x (theta separability); blocks 1.. stage
// A=[S|z0] (fp64) and Sp = 16B-aligned padded fp32 copy of S for combine.
// ---------------------------------------------------------------------------
__global__ __launch_bounds__(512) void prep_kernel(const float* __restrict__ x,
                                                   const float* __restrict__ S,
                                                   const float* __restrict__ z0,
                                                   void* __restrict__ wsv) {
  const int tid = threadIdx.x;
  if (blockIdx.x == 0) {
    const int wave = tid >> 6, lane = tid & 63;
    const int b = wave >> 1, comp = wave & 1;
    const float* xp = x + ((size_t)b * LL) * 2 + comp;
    double loc[8];
    double run = 0.0;
    #pragma unroll
    for (int e = 0; e < 8; ++e) {
      run += (double)xp[(lane * 8 + e) * 2];
      loc[e] = run;
    }
    double tot = run;
    #pragma unroll
    for (int off = 1; off < 64; off <<= 1) {
      const double o = __shfl_up(tot, off);
      if (lane >= off) tot += o;
    }
    const double excl = tot - run;
    float* cp = (float*)((char*)wsv + CXY_BYTE) + ((size_t)b * LL) * 2 + comp;
    #pragma unroll
    for (int e = 0; e < 8; ++e)
      cp[(lane * 8 + e) * 2] = (float)(excl + loc[e]);
    return;
  }
  double* A  = (double*)((char*)wsv + A_BYTE);
  float*  Sp = (float*)((char*)wsv + SP_BYTE);
  const int g = (blockIdx.x - 1) * 512 + tid;
  if (g < N * AP) {
    const int i = g / AP, j = g - i * AP;
    A[g] = (double)((j < N) ? S[i * N + j] : z0[i]);
  } else {
    const int s2 = g - N * AP;
    if (s2 < N * SPSTR) {
      const int i = s2 / SPSTR, d = s2 - i * SPSTR;
      Sp[s2] = (d < N) ? S[i * N + d] : 0.0f;
    }
  }
}

// ---------------------------------------------------------------------------
// pivot kernel (ns blocks, 256 thr): per panel, each block redundantly
// computes Binv = inv(diag 64x64) then Jordan-normalizes its 64-col slice of
// the pivot rows:  Wv = Binv * A_old[pivot, slice] -> A + U12w.
//  - 64x64 LU in REGISTERS on wave 0 (shfl, compile-time lanes)
//  - invL (wave 0) / invU (wave 1) columns with FIXED-bound loops in LDS
//  - Binv = invU*invL (all 256 threads), then the slice product
// ---------------------------------------------------------------------------
__global__ __launch_bounds__(256) void pivot_kernel(void* __restrict__ wsv,
                                                    int k0, int tc2) {
  __shared__ __align__(16) double Bsh[NBK * 65];
  __shared__ __align__(16) double iLs[NBK * 65];
  __shared__ __align__(16) double iUs[NBK * 65];
  __shared__ __align__(16) double Ao [NBK * 66];
  __shared__ double rd[NBK];
  double* A    = (double*)((char*)wsv + A_BYTE);
  double* U12w = (double*)((char*)wsv + U12_BYTE);
  const int tid = threadIdx.x;
  const int ct  = k0 + NBK;
  const int c0  = blockIdx.x * 64;
  const int cc  = (tc2 - c0 < 64) ? (tc2 - c0) : 64;

  // load diag block + this block's slice of pivot-row trailing cols
  for (int idx = tid; idx < NBK * NBK; idx += 256) {
    const int i = idx >> 6, c = idx & 63;
    Bsh[i * 65 + c] = A[(k0 + i) * AP + k0 + c];
    Ao [i * 66 + c] = (c < cc) ? A[(k0 + i) * AP + ct + c0 + c] : 0.0;
  }
  __syncthreads();

  // register LU on wave 0
  if (tid < 64) {
    double r[NBK];
    #pragma unroll
    for (int c = 0; c < NBK; ++c) r[c] = Bsh[tid * 65 + c];
    #pragma unroll
    for (int j = 0; j < NBK; ++j) {
      const double ujj = __shfl(r[j], j);
      const double m = r[j] / ujj;
      #pragma unroll
      for (int j2 = j + 1; j2 < NBK; ++j2) {
        const double u = __shfl(r[j2], j);
        if (tid > j) r[j2] -= m * u;
      }
      if (tid > j) r[j] = m;
    }
    #pragma unroll
    for (int c = 0; c < NBK; ++c) Bsh[tid * 65 + c] = r[c];
  }
  __syncthreads();
  if (tid < 64) rd[tid] = 1.0 / Bsh[tid * 65 + tid];
  __syncthreads();

  // triangular inverses, fixed-bound loops (no per-thread runtime bounds)
  if (tid < 64) {
    const int e = tid;                       // invL column e (unit lower)
    for (int i = 0; i < NBK; ++i) {
      double v = (i == e) ? 1.0 : 0.0;
      for (int t = 0; t < i; ++t) v -= Bsh[i * 65 + t] * iLs[t * 65 + e];
      iLs[i * 65 + e] = v;                   // rows i<e come out exactly 0
    }
  } else if (tid < 128) {
    const int e = tid - 64;                  // invU column e
    for (int i = NBK - 1; i >= 0; --i) {
      double v = (i == e) ? 1.0 : 0.0;
      for (int t = i + 1; t < NBK; ++t) v -= Bsh[i * 65 + t] * iUs[t * 65 + e];
      iUs[i * 65 + e] = v * rd[i];           // rows i>e come out exactly 0
    }
  }
  __syncthreads();

  // Binv = iU * iL  -> overwrite Bsh
  {
    const int i = tid >> 2, j0 = (tid & 3) * 16;
    double acc[16];
    #pragma unroll
    for (int e = 0; e < 16; ++e) acc[e] = 0.0;
    for (int t = 0; t < NBK; ++t) {
      const double uv = iUs[i * 65 + t];
      #pragma unroll
      for (int e = 0; e < 16; ++e) acc[e] += uv * iLs[t * 65 + j0 + e];
    }
    __syncthreads();
    #pragma unroll
    for (int e = 0; e < 16; ++e) Bsh[i * 65 + j0 + e] = acc[e];
  }
  __syncthreads();

  // Wv = Binv * Ao -> A pivot rows + U12w (this block's col slice)
  {
    const int i = tid >> 2, j0 = (tid & 3) * 16;
    double acc[16];
    #pragma unroll
    for (int e = 0; e < 16; ++e) acc[e] = 0.0;
    for (int t = 0; t < NBK; ++t) {
      const double bv = Bsh[i * 65 + t];
      #pragma unroll
      for (int e = 0; e < 16; ++e) acc[e] += bv * Ao[t * 66 + j0 + e];
    }
    #pragma unroll
    for (int e = 0; e < 16; ++e) {
      const int c = j0 + e;
      if (c < cc) {
        A[(k0 + i) * AP + ct + c0 + c] = acc[e];
        U12w[i * USTR + c0 + c] = acc[e];
      }
    }
  }
}

// ---------------------------------------------------------------------------
// rank kernel (grid 4 x ns, 256 thr): non-pivot rows R = [0,k0) U [ct,N):
//   A[gr, ct+c] -= sum_t A[gr, k0+t] * U12w[t][c]     (4x4 microtiles)
// ---------------------------------------------------------------------------
__global__ __launch_bounds__(256) void rank_kernel(void* __restrict__ wsv,
                                                   int k0, int tc2) {
  __shared__ __align__(16) double PlT[NBK * 66];   // [t][r]
  __shared__ __align__(16) double Ul [NBK * 68];   // [t][c]
  double* A = (double*)((char*)wsv + A_BYTE);
  const double* U12w = (const double*)((const char*)wsv + U12_BYTE);
  const int tid = threadIdx.x;
  const int ct  = k0 + NBK;
  const int rb0 = blockIdx.x * 64;
  const int c0  = blockIdx.y * 64;
  const int NR  = N - NBK;   // 193 non-pivot rows

  for (int idx = tid; idx < NBK * NBK; idx += 256) {
    const int r = idx >> 6, t = idx & 63;
    const int rb = rb0 + r;
    const int gr = (rb < k0) ? rb : rb + NBK;
    PlT[t * 66 + r] = (rb < NR) ? A[gr * AP + k0 + t] : 0.0;
    Ul [r * 68 + t] = (c0 + t < tc2) ? U12w[r * USTR + c0 + t] : 0.0;
  }
  __syncthreads();

  const int r0 = (tid >> 4) * 4;
  const int c4 = (tid & 15) * 4;
  int grs[4]; bool rok[4];
  #pragma unroll
  for (int rr = 0; rr < 4; ++rr) {
    const int rb = rb0 + r0 + rr;
    rok[rr] = rb < NR;
    grs[rr] = (rb < k0) ? rb : rb + NBK;
  }
  double acc[4][4];
  #pragma unroll
  for (int rr = 0; rr < 4; ++rr)
    #pragma unroll
    for (int c = 0; c < 4; ++c)
      acc[rr][c] = (rok[rr] && (c0 + c4 + c) < tc2)
                 ? A[grs[rr] * AP + ct + c0 + c4 + c] : 0.0;

  for (int t = 0; t < NBK; ++t) {
    const double2 p01 = *(const double2*)&PlT[t * 66 + r0];
    const double2 p23 = *(const double2*)&PlT[t * 66 + r0 + 2];
    const double2 u01 = *(const double2*)&Ul[t * 68 + c4];
    const double2 u23 = *(const double2*)&Ul[t * 68 + c4 + 2];
    acc[0][0] -= p01.x*u01.x; acc[0][1] -= p01.x*u01.y; acc[0][2] -= p01.x*u23.x; acc[0][3] -= p01.x*u23.y;
    acc[1][0] -= p01.y*u01.x; acc[1][1] -= p01.y*u01.y; acc[1][2] -= p01.y*u23.x; acc[1][3] -= p01.y*u23.y;
    acc[2][0] -= p23.x*u01.x; acc[2][1] -= p23.x*u01.y; acc[2][2] -= p23.x*u23.x; acc[2][3] -= p23.x*u23.y;
    acc[3][0] -= p23.y*u01.x; acc[3][1] -= p23.y*u01.y; acc[3][2] -= p23.y*u23.x; acc[3][3] -= p23.y*u23.y;
  }
  #pragma unroll
  for (int rr = 0; rr < 4; ++rr)
    #pragma unroll
    for (int c = 0; c < 4; ++c)
      if (rok[rr] && (c0 + c4 + c) < tc2)
        A[grs[rr] * AP + ct + c0 + c4 + c] = acc[rr][c];
}

// ---------------------------------------------------------------------------
// finish: rows 0..255 Jordan-normalized (unit diagonal):
//   x256 = rhs256/A[256][256];  w0[k] = rhs[k] - A[k][256]*x256
// ---------------------------------------------------------------------------
__global__ __launch_bounds__(256) void finish_kernel(void* __restrict__ wsv) {
  __shared__ double xs256;
  double* A   = (double*)((char*)wsv + A_BYTE);
  float*  w0f = (float*)((char*)wsv + W0_BYTE);
  const int tid = threadIdx.x;
  if (tid == 0) xs256 = A[256 * AP + 257] / A[256 * AP + 256];
  __syncthreads();
  const double x256 = xs256;
  w0f[tid] = (float)(A[tid * AP + 257] - A[tid * AP + 256] * x256);
  if (tid == 0) w0f[256] = (float)x256;
}

// ---------------------------------------------------------------------------
// combine: tiled GEMM  out[(b,l), i] = sum_d W[(b,l),d] * S[i,d]
// block = 64 l x 64 i, full K=257 in LDS; W built on the fly from w0+angles.
// ---------------------------------------------------------------------------
__global__ __launch_bounds__(256) void combine_kernel(const float* __restrict__ om,
                                                      const void* __restrict__ wsv,
                                                      float* __restrict__ out) {
  __shared__ __align__(16) float STs[N * 68];   // [d][i]
  __shared__ __align__(16) float WT [N * 68];   // [d][l]
  __shared__ float omsh[2 * MM];
  __shared__ float w0sh[N];
  __shared__ float cxl[64], cyl[64];
  const int tid = threadIdx.x;
  const int gl0 = blockIdx.x * 64;
  const int i0  = blockIdx.y * 64;
  const float* w0  = (const float*)((const char*)wsv + W0_BYTE);
  const float* cxy = (const float*)((const char*)wsv + CXY_BYTE);
  const float* Sp  = (const float*)((const char*)wsv + SP_BYTE);

  for (int idx = tid; idx < 2 * MM; idx += 256) omsh[idx] = om[idx];
  for (int idx = tid; idx < N; idx += 256) w0sh[idx] = w0[idx];
  if (tid < 64) {
    cxl[tid] = cxy[(gl0 + tid) * 2];
    cyl[tid] = cxy[(gl0 + tid) * 2 + 1];
  }
  for (int idx = tid; idx < 64 * SPSTR; idx += 256) {
    const int ii = idx / SPSTR, d = idx - ii * SPSTR;
    if (d < N) {
      const int gi = i0 + ii;
      STs[d * 68 + ii] = (gi < N) ? Sp[gi * SPSTR + d] : 0.0f;
    }
  }
  __syncthreads();

  for (int idx = tid; idx < 64 * N; idx += 256) {
    const int l = idx & 63, d = idx >> 6;
    float v;
    if (d == 0) {
      v = w0sh[0];
    } else {
      const int m = (d - 1) >> 1, pq = 2 * m + 1;
      const float t = cxl[l] * omsh[2 * m] + cyl[l] * omsh[2 * m + 1];
      float s, c;
      sincosf(t, &s, &c);
      v = (d & 1) ? (c * w0sh[pq] - s * w0sh[pq + 1])
                  : (s * w0sh[pq] + c * w0sh[pq + 1]);
    }
    WT[d * 68 + l] = v;
  }
  __syncthreads();

  const int ti = tid & 15, tl = tid >> 4;
  float acc[4][4];
  #pragma unroll
  for (int a = 0; a < 4; ++a)
    #pragma unroll
    for (int b2 = 0; b2 < 4; ++b2) acc[a][b2] = 0.0f;

  for (int d = 0; d < N; ++d) {
    const float4 wv = *(const float4*)&WT[d * 68 + tl * 4];
    const float4 sv = *(const float4*)&STs[d * 68 + ti * 4];
    acc[0][0] += wv.x*sv.x; acc[0][1] += wv.x*sv.y; acc[0][2] += wv.x*sv.z; acc[0][3] += wv.x*sv.w;
    acc[1][0] += wv.y*sv.x; acc[1][1] += wv.y*sv.y; acc[1][2] += wv.y*sv.z; acc[1][3] += wv.y*sv.w;
    acc[2][0] += wv.z*sv.x; acc[2][1] += wv.z*sv.y; acc[2][2] += wv.z*sv.z; acc[2][3] += wv.z*sv.w;
    acc[3][0] += wv.w*sv.x; acc[3][1] += wv.w*sv.y; acc[3][2] += wv.w*sv.z; acc[3][3] += wv.w*sv.w;
  }

  #pragma unroll
  for (int li = 0; li < 4; ++li) {
    const int gl = gl0 + tl * 4 + li;
    #pragma unroll
    for (int si = 0; si < 4; ++si) {
      const int iv = i0 + ti * 4 + si;
      if (iv < N) {
        out[(size_t)gl * N + iv] = acc[li][si];
        if ((gl & (LL - 1)) == LL - 1)
          out[(size_t)BB * LL * N + (size_t)(gl >> 9) * N + iv] = acc[li][si];
      }
    }
  }
}

extern "C" void kernel_launch(void* const* d_in, const int* in_sizes, int n_in,
                              void* d_out, int out_size, void* d_ws, size_t ws_size,
                              hipStream_t stream) {
  const float* x  = (const float*)d_in[0];   // (B, L, 2)
  const float* z0 = (const float*)d_in[1];   // (D,)
  const float* om = (const float*)d_in[2];   // (M, 2)
  const float* S  = (const float*)d_in[3];   // (D, D)
  float* out = (float*)d_out;                // outputs (B,L,D) then z_final (B,D)

  hipLaunchKernelGGL(prep_kernel, dim3(262), dim3(512), 0, stream, x, S, z0, d_ws);
  for (int p = 0; p < 4; ++p) {
    const int k0  = p * NBK;
    const int tc2 = 258 - (k0 + NBK);
    const int ns  = (tc2 + 63) / 64;
    hipLaunchKernelGGL(pivot_kernel, dim3(ns),      dim3(256), 0, stream, d_ws, k0, tc2);
    hipLaunchKernelGGL(rank_kernel,  dim3(4, ns),   dim3(256), 0, stream, d_ws, k0, tc2);
  }
  hipLaunchKernelGGL(finish_kernel, dim3(1), dim3(256), 0, stream, d_ws);
  hipLaunchKernelGGL(combine_kernel, dim3(LL * BB / 64, 5), dim3(256), 0, stream, om, d_ws, out);
}